// Round 2
// baseline (6074.532 us; speedup 1.0000x reference)
//
#include <hip/hip_runtime.h>
#include <math.h>

// Problem constants: B=8, T=2048, D=1024, K_SIZE=1024, all fp32.
#define B_   8
#define T_   2048
#define D_   1024
#define KSZ  1024
#define CH   256            // i-rows per S chunk
#define NCH  (T_ / CH)      // 8 chunks

// GEMM tiling: 128x128 block, BK=8, 256 threads, 8x8 micro-tile per thread.
#define BM 128
#define BN 128
#define BK 8
#define TM 8
#define TN 8
#define NT 256

// ---------------------------------------------------------------------------
// K1: C[M,N] = A[M,Kd] @ W[Kd,N] + bias[N]   (row-major everywhere)
// ---------------------------------------------------------------------------
__global__ __launch_bounds__(NT)
void sgemm_bias_kernel(const float* __restrict__ A, const float* __restrict__ W,
                       const float* __restrict__ bias, float* __restrict__ C,
                       int M, int N, int Kd) {
  __shared__ float As[BK][BM];   // A staged transposed: As[k][m]
  __shared__ float Bs[BK][BN];   // Bs[k][n]
  const int tid  = threadIdx.x;
  const int row0 = blockIdx.y * BM;
  const int col0 = blockIdx.x * BN;
  const int tx = tid & 15, ty = tid >> 4;
  const int arow = tid >> 1,  acol = (tid & 1) * 4;
  const int brow = tid >> 5,  bcol = (tid & 31) * 4;

  float acc[TM][TN] = {};
  const float* aptr = A + (size_t)(row0 + arow) * Kd + acol;
  const float* wptr = W + (size_t)brow * N + col0 + bcol;

  for (int k0 = 0; k0 < Kd; k0 += BK) {
    float4 av = *(const float4*)(aptr + k0);
    float4 bv = *(const float4*)(wptr + (size_t)k0 * N);
    __syncthreads();
    As[acol + 0][arow] = av.x; As[acol + 1][arow] = av.y;
    As[acol + 2][arow] = av.z; As[acol + 3][arow] = av.w;
    *(float4*)&Bs[brow][bcol] = bv;
    __syncthreads();
#pragma unroll
    for (int kk = 0; kk < BK; ++kk) {
      float4 a0 = *(const float4*)&As[kk][ty * TM];
      float4 a1 = *(const float4*)&As[kk][ty * TM + 4];
      float4 b0 = *(const float4*)&Bs[kk][tx * TN];
      float4 b1 = *(const float4*)&Bs[kk][tx * TN + 4];
      float af[TM] = {a0.x, a0.y, a0.z, a0.w, a1.x, a1.y, a1.z, a1.w};
      float bf[TN] = {b0.x, b0.y, b0.z, b0.w, b1.x, b1.y, b1.z, b1.w};
#pragma unroll
      for (int i = 0; i < TM; ++i)
#pragma unroll
        for (int j = 0; j < TN; ++j)
          acc[i][j] = fmaf(af[i], bf[j], acc[i][j]);
    }
  }
#pragma unroll
  for (int i = 0; i < TM; ++i) {
    const int r = row0 + ty * TM + i;
#pragma unroll
    for (int j = 0; j < TN; j += 4) {
      const int c = col0 + tx * TN + j;
      float4 o;
      o.x = acc[i][j + 0] + bias[c + 0];
      o.y = acc[i][j + 1] + bias[c + 1];
      o.z = acc[i][j + 2] + bias[c + 2];
      o.w = acc[i][j + 3] + bias[c + 3];
      *(float4*)&C[(size_t)r * N + c] = o;
    }
  }
}

// ---------------------------------------------------------------------------
// K2: Schunk[b, il, j] = Q[b, c*CH+il, :] . K[b, j, :] for tiles jt <= it.
// Diagonal tiles computed fully (masked later); upper tiles never touched.
// ---------------------------------------------------------------------------
__global__ __launch_bounds__(NT)
void qk_chunk_kernel(const float* __restrict__ Q, const float* __restrict__ Km,
                     float* __restrict__ Sc, int c) {
  const int jt = blockIdx.x, itl = blockIdx.y, b = blockIdx.z;
  const int itg = c * (CH / BM) + itl;       // global 128-row tile index
  if (jt > itg) return;
  const float* Qb = Q  + (size_t)b * T_ * KSZ;
  const float* Kb = Km + (size_t)b * T_ * KSZ;
  float*       Sb = Sc + (size_t)b * CH * T_;

  __shared__ float As[BK][BM];
  __shared__ float Bs[BK][BN];
  const int tid  = threadIdx.x;
  const int grow0 = itg * BM;                // global Q row base
  const int lrow0 = itl * BM;                // local Schunk row base
  const int col0  = jt * BN;
  const int tx = tid & 15, ty = tid >> 4;
  const int lrow = tid >> 1, lcol = (tid & 1) * 4;

  float acc[TM][TN] = {};
  const float* qptr = Qb + (size_t)(grow0 + lrow) * KSZ + lcol;
  const float* kptr = Kb + (size_t)(col0 + lrow) * KSZ + lcol;

  for (int k0 = 0; k0 < KSZ; k0 += BK) {
    float4 av = *(const float4*)(qptr + k0);
    float4 bv = *(const float4*)(kptr + k0);
    __syncthreads();
    As[lcol + 0][lrow] = av.x; As[lcol + 1][lrow] = av.y;
    As[lcol + 2][lrow] = av.z; As[lcol + 3][lrow] = av.w;
    Bs[lcol + 0][lrow] = bv.x; Bs[lcol + 1][lrow] = bv.y;
    Bs[lcol + 2][lrow] = bv.z; Bs[lcol + 3][lrow] = bv.w;
    __syncthreads();
#pragma unroll
    for (int kk = 0; kk < BK; ++kk) {
      float4 a0 = *(const float4*)&As[kk][ty * TM];
      float4 a1 = *(const float4*)&As[kk][ty * TM + 4];
      float4 b0 = *(const float4*)&Bs[kk][tx * TN];
      float4 b1 = *(const float4*)&Bs[kk][tx * TN + 4];
      float af[TM] = {a0.x, a0.y, a0.z, a0.w, a1.x, a1.y, a1.z, a1.w};
      float bf[TN] = {b0.x, b0.y, b0.z, b0.w, b1.x, b1.y, b1.z, b1.w};
#pragma unroll
      for (int i = 0; i < TM; ++i)
#pragma unroll
        for (int j = 0; j < TN; ++j)
          acc[i][j] = fmaf(af[i], bf[j], acc[i][j]);
    }
  }
#pragma unroll
  for (int i = 0; i < TM; ++i) {
    const int r = lrow0 + ty * TM + i;
#pragma unroll
    for (int j = 0; j < TN; j += 4) {
      const int cc = col0 + tx * TN + j;
      float4 o = {acc[i][j], acc[i][j + 1], acc[i][j + 2], acc[i][j + 3]};
      *(float4*)&Sb[(size_t)r * T_ + cc] = o;
    }
  }
}

// ---------------------------------------------------------------------------
// K3a: per-column (j) online max/sum over this chunk's i rows (i >= j only).
// ---------------------------------------------------------------------------
__global__ __launch_bounds__(256)
void colstats_partial(const float* __restrict__ Sc, float* __restrict__ pm,
                      float* __restrict__ pd, int c) {
  const int j = blockIdx.x * 256 + threadIdx.x;
  const int b = blockIdx.y;
  const float* Sb = Sc + (size_t)b * CH * T_;
  float m = -INFINITY, d = 0.f;
  for (int ii = 0; ii < CH; ++ii) {
    const int i = c * CH + ii;
    if (i >= j) {
      const float v = Sb[(size_t)ii * T_ + j];
      const float nm = fmaxf(m, v);
      d = d * expf(m - nm) + expf(v - nm);
      m = nm;
    }
  }
  const int idx = (c * B_ + b) * T_ + j;
  pm[idx] = m;
  pd[idx] = d;
}

// K3a2: combine NCH partials per column; fold 1/sqrt(K)=1/32 into rcol.
__global__ __launch_bounds__(256)
void colstats_combine(const float* __restrict__ pm, const float* __restrict__ pd,
                      float* __restrict__ mcol, float* __restrict__ rcol) {
  const int j = blockIdx.x * 256 + threadIdx.x;
  const int b = blockIdx.y;
  float m = -INFINITY, d = 0.f;
  for (int c = 0; c < NCH; ++c) {
    const int idx = (c * B_ + b) * T_ + j;
    const float pmv = pm[idx], pdv = pd[idx];
    if (pdv > 0.f) {
      const float nm = fmaxf(m, pmv);
      d = d * expf(m - nm) + pdv * expf(pmv - nm);
      m = nm;
    }
  }
  mcol[b * T_ + j] = m;
  rcol[b * T_ + j] = 1.f / (d * 32.f);
}

// ---------------------------------------------------------------------------
// K3b: in-place P = exp(S - m_j) * rcol_j for j <= i, 0 for j > i (diag tiles).
// ---------------------------------------------------------------------------
__global__ __launch_bounds__(256)
void normalize_chunk(float* __restrict__ Sc, const float* __restrict__ mcol,
                     const float* __restrict__ rcol, int c) {
  const int jt = blockIdx.x, itl = blockIdx.y, b = blockIdx.z;
  const int itg = c * (CH / 128) + itl;
  if (jt > itg) return;
  float* Sb = Sc + (size_t)b * CH * T_;
  const int li0 = itl * 128, gi0 = itg * 128, j0 = jt * 128;
#pragma unroll 4
  for (int r = 0; r < 64; ++r) {
    const int idx = r * 256 + threadIdx.x;
    const int li = idx >> 7, lj = idx & 127;
    const int gi = gi0 + li, j = j0 + lj;
    const size_t off = (size_t)(li0 + li) * T_ + j;
    float v = 0.f;
    if (j <= gi)
      v = expf(Sb[off] - mcol[b * T_ + j]) * rcol[b * T_ + j];
    Sb[off] = v;
  }
}

// ---------------------------------------------------------------------------
// K4: out[b,gi,v] = X[b,gi,v] + sum_{j<=gi} P[gi,j] * V[b,j,v]
// ---------------------------------------------------------------------------
__global__ __launch_bounds__(NT)
void pv_chunk_kernel(const float* __restrict__ Sc, const float* __restrict__ V,
                     const float* __restrict__ X, float* __restrict__ out, int c) {
  const int vt = blockIdx.x, itl = blockIdx.y, b = blockIdx.z;
  const int itg = c * (CH / BM) + itl;
  const float* Pb = Sc + (size_t)b * CH * T_;
  const float* Vb = V  + (size_t)b * T_ * D_;

  __shared__ float As[BK][BM];
  __shared__ float Bs[BK][BN];
  const int tid  = threadIdx.x;
  const int lrow0 = itl * BM, grow0 = itg * BM, col0 = vt * BN;
  const int tx = tid & 15, ty = tid >> 4;
  const int arow = tid >> 1, acol = (tid & 1) * 4;
  const int brow = tid >> 5, bcol = (tid & 31) * 4;

  float acc[TM][TN] = {};
  const int kmax = (itg + 1) * BM;     // j <= i ⇒ only tiles up to the diagonal
  const float* pptr = Pb + (size_t)(lrow0 + arow) * T_ + acol;
  const float* vptr = Vb + (size_t)brow * D_ + col0 + bcol;

  for (int k0 = 0; k0 < kmax; k0 += BK) {
    float4 av = *(const float4*)(pptr + k0);
    float4 bv = *(const float4*)(vptr + (size_t)k0 * D_);
    __syncthreads();
    As[acol + 0][arow] = av.x; As[acol + 1][arow] = av.y;
    As[acol + 2][arow] = av.z; As[acol + 3][arow] = av.w;
    *(float4*)&Bs[brow][bcol] = bv;
    __syncthreads();
#pragma unroll
    for (int kk = 0; kk < BK; ++kk) {
      float4 a0 = *(const float4*)&As[kk][ty * TM];
      float4 a1 = *(const float4*)&As[kk][ty * TM + 4];
      float4 b0 = *(const float4*)&Bs[kk][tx * TN];
      float4 b1 = *(const float4*)&Bs[kk][tx * TN + 4];
      float af[TM] = {a0.x, a0.y, a0.z, a0.w, a1.x, a1.y, a1.z, a1.w};
      float bf[TN] = {b0.x, b0.y, b0.z, b0.w, b1.x, b1.y, b1.z, b1.w};
#pragma unroll
      for (int i = 0; i < TM; ++i)
#pragma unroll
        for (int j = 0; j < TN; ++j)
          acc[i][j] = fmaf(af[i], bf[j], acc[i][j]);
    }
  }
#pragma unroll
  for (int i = 0; i < TM; ++i) {
    const int r = grow0 + ty * TM + i;
#pragma unroll
    for (int j = 0; j < TN; j += 4) {
      const int cc = col0 + tx * TN + j;
      const size_t o = ((size_t)b * T_ + r) * D_ + cc;
      float4 xv = *(const float4*)&X[o];
      float4 ov;
      ov.x = acc[i][j + 0] + xv.x;
      ov.y = acc[i][j + 1] + xv.y;
      ov.z = acc[i][j + 2] + xv.z;
      ov.w = acc[i][j + 3] + xv.w;
      *(float4*)&out[o] = ov;
    }
  }
}

// ---------------------------------------------------------------------------
extern "C" void kernel_launch(void* const* d_in, const int* in_sizes, int n_in,
                              void* d_out, int out_size, void* d_ws, size_t ws_size,
                              hipStream_t stream) {
  const float* X  = (const float*)d_in[0];
  const float* Wq = (const float*)d_in[1];
  const float* bq = (const float*)d_in[2];
  const float* Wk = (const float*)d_in[3];
  const float* bk = (const float*)d_in[4];
  const float* Wv = (const float*)d_in[5];
  const float* bv = (const float*)d_in[6];
  float* out = (float*)d_out;

  // Workspace (floats): Q | K | V | Schunk | pm | pd | mcol | rcol ≈ 219 MB.
  float* ws   = (float*)d_ws;
  float* Q    = ws;
  float* Kp   = Q    + (size_t)B_ * T_ * KSZ;
  float* Vp   = Kp   + (size_t)B_ * T_ * KSZ;
  float* Sc   = Vp   + (size_t)B_ * T_ * D_;
  float* pm   = Sc   + (size_t)B_ * CH * T_;
  float* pd   = pm   + (size_t)NCH * B_ * T_;
  float* mcol = pd   + (size_t)NCH * B_ * T_;
  float* rcol = mcol + (size_t)B_ * T_;

  const dim3 blk(NT);
  const int M = B_ * T_;

  // Projections
  sgemm_bias_kernel<<<dim3(KSZ / BN, M / BM), blk, 0, stream>>>(X, Wq, bq, Q, M, KSZ, D_);
  sgemm_bias_kernel<<<dim3(KSZ / BN, M / BM), blk, 0, stream>>>(X, Wk, bk, Kp, M, KSZ, D_);
  sgemm_bias_kernel<<<dim3(D_ / BN, M / BM), blk, 0, stream>>>(X, Wv, bv, Vp, M, D_, D_);

  // Pass A: column softmax stats (softmax over query axis i, valid i >= j)
  for (int c = 0; c < NCH; ++c) {
    qk_chunk_kernel<<<dim3(T_ / BN, CH / BM, B_), blk, 0, stream>>>(Q, Kp, Sc, c);
    colstats_partial<<<dim3(T_ / 256, B_), blk, 0, stream>>>(Sc, pm, pd, c);
  }
  colstats_combine<<<dim3(T_ / 256, B_), blk, 0, stream>>>(pm, pd, mcol, rcol);

  // Pass B: recompute S per chunk, normalize, PV + residual
  for (int c = 0; c < NCH; ++c) {
    qk_chunk_kernel<<<dim3(T_ / BN, CH / BM, B_), blk, 0, stream>>>(Q, Kp, Sc, c);
    normalize_chunk<<<dim3(T_ / 128, CH / 128, B_), blk, 0, stream>>>(Sc, mcol, rcol, c);
    pv_chunk_kernel<<<dim3(D_ / BN, CH / BM, B_), blk, 0, stream>>>(Sc, Vp, X, out, c);
  }
}

// Round 3
// 1003.935 us; speedup vs baseline: 6.0507x; 6.0507x over previous
//
#include <hip/hip_runtime.h>
#include <hip/hip_fp16.h>
#include <math.h>

// Problem constants: B=8, T=2048, D=1024, K_SIZE=1024, fp32 in/out.
#define B_   8
#define T_   2048
#define D_   1024
#define KSZ  1024
#define CH   512            // i-rows per S chunk
#define NCHUNK 4            // T_/CH
#define NSLOT 16            // T_/128 softmax partial slots

typedef _Float16 f16;
typedef _Float16 f16x8 __attribute__((ext_vector_type(8)));
typedef _Float16 f16x4 __attribute__((ext_vector_type(4)));
typedef float f32x4 __attribute__((ext_vector_type(4)));

// ---------------------------------------------------------------------------
// Prep: fp32 -> fp16 cast (vectorized)
// ---------------------------------------------------------------------------
__global__ __launch_bounds__(256)
void cast_f16_kernel(const float* __restrict__ X, f16* __restrict__ Xh) {
  const size_t i = ((size_t)blockIdx.x * 256 + threadIdx.x) * 4;
  float4 v = *(const float4*)&X[i];
  f16x4 o = {(f16)v.x, (f16)v.y, (f16)v.z, (f16)v.w};
  *(f16x4*)&Xh[i] = o;
}

// Prep: W[k][n] -> Wt[n][k] fp16 (1024x1024)
__global__ __launch_bounds__(256)
void transcast_kernel(const float* __restrict__ W, f16* __restrict__ Wt) {
  const int idx = blockIdx.x * 256 + threadIdx.x;  // idx = n*1024 + k, k fast
  const int n = idx >> 10, k = idx & 1023;
  Wt[idx] = (f16)W[k * 1024 + n];
}

// ---------------------------------------------------------------------------
// Unified fp16 MFMA NT-GEMM: C[m,n] = sum_k A[m,k] * B[n,k]  (+ epilogue)
//  EP=0: proj Q/K  -> Oh fp16 [16384][1024], +bias
//  EP=1: proj V    -> Vt fp16 [b][v][t] (transposed store), +bias
//  EP=2: QK chunk  -> Of fp32 S[b][CH][T_], triangular tile skip
//  EP=3: PV chunk  -> Of fp32 out[b][t][v] = acc + Resid (residual X)
// Both operands staged [128 rows][32 k] in LDS (padded stride 40).
// Verified fragment recipe (m91/m97): A/B frag = row(lane&15), k(quad*8+j);
// C/D: row=(lane>>4)*4+reg (A-side), col=lane&15 (B-side).
// ---------------------------------------------------------------------------
template <int EP>
__global__ __launch_bounds__(256)
void gemm_nt(const f16* __restrict__ A, const f16* __restrict__ Bm,
             const float* __restrict__ bias, f16* __restrict__ Oh,
             float* __restrict__ Of, const float* __restrict__ Resid,
             int rowTileOff) {
  constexpr int LDA = (EP == 3) ? T_ : KSZ;
  constexpr int LDB = (EP == 3) ? T_ : KSZ;
  const int jt = blockIdx.x, it = blockIdx.y, b = blockIdx.z;
  const int itg = rowTileOff + it;
  if (EP == 2 && jt > itg) return;
  const int kend = (EP == 3) ? (itg + 1) * 128 : KSZ;

  const f16* Ab = A;
  const f16* Bb = Bm;
  if (EP == 2) { Ab += (size_t)b * T_ * KSZ; Bb += (size_t)b * T_ * KSZ; }
  if (EP == 3) { Ab += (size_t)b * CH * T_;  Bb += (size_t)b * D_ * T_; }

  const int arow0 = (EP == 2) ? itg * 128 : it * 128;  // EP3: local chunk rows
  const int col0 = jt * 128;

  __shared__ f16 Ash[128 * 40];
  __shared__ f16 Bsh[128 * 40];

  const int tid = threadIdx.x;
  const int trow = tid >> 1, tk = (tid & 1) * 16;
  const f16* ag = Ab + (size_t)(arow0 + trow) * LDA + tk;
  const f16* bg = Bb + (size_t)(col0 + trow) * LDB + tk;

  const int lane = tid & 63, wv = tid >> 6;
  const int wm = (wv & 1) * 64, wn = (wv >> 1) * 64;
  const int fr = lane & 15, quad = lane >> 4;

  f32x4 acc[4][4] = {};

  for (int k0 = 0; k0 < kend; k0 += 32) {
    float4 a0 = *(const float4*)(ag + k0);
    float4 a1 = *(const float4*)(ag + k0 + 8);
    float4 b0 = *(const float4*)(bg + k0);
    float4 b1 = *(const float4*)(bg + k0 + 8);
    __syncthreads();
    *(float4*)&Ash[trow * 40 + tk]     = a0;
    *(float4*)&Ash[trow * 40 + tk + 8] = a1;
    *(float4*)&Bsh[trow * 40 + tk]     = b0;
    *(float4*)&Bsh[trow * 40 + tk + 8] = b1;
    __syncthreads();
    f16x8 af[4], bf[4];
#pragma unroll
    for (int mi = 0; mi < 4; ++mi)
      af[mi] = *(const f16x8*)&Ash[(wm + mi * 16 + fr) * 40 + quad * 8];
#pragma unroll
    for (int ni = 0; ni < 4; ++ni)
      bf[ni] = *(const f16x8*)&Bsh[(wn + ni * 16 + fr) * 40 + quad * 8];
#pragma unroll
    for (int mi = 0; mi < 4; ++mi)
#pragma unroll
      for (int ni = 0; ni < 4; ++ni)
        acc[mi][ni] = __builtin_amdgcn_mfma_f32_16x16x32_f16(af[mi], bf[ni], acc[mi][ni], 0, 0, 0);
  }

#pragma unroll
  for (int mi = 0; mi < 4; ++mi) {
#pragma unroll
    for (int ni = 0; ni < 4; ++ni) {
      const int col = col0 + wn + ni * 16 + fr;
      float bc = 0.f;
      if (EP == 0 || EP == 1) bc = bias[col];
      const int r0 = wm + mi * 16 + quad * 4;
      f32x4 v = acc[mi][ni];
      if (EP == 0) {
        const int grow = it * 128 + r0;
#pragma unroll
        for (int rg = 0; rg < 4; ++rg)
          Oh[(size_t)(grow + rg) * KSZ + col] = (f16)(v[rg] + bc);
      } else if (EP == 1) {
        const int grow = it * 128 + r0;
        const int bb = grow >> 11, t0 = grow & 2047;
        f16x4 pk;
#pragma unroll
        for (int rg = 0; rg < 4; ++rg) pk[rg] = (f16)(v[rg] + bc);
        *(f16x4*)&Oh[((size_t)bb * D_ + col) * T_ + t0] = pk;
      } else if (EP == 2) {
        const int lrow = it * 128 + r0;
#pragma unroll
        for (int rg = 0; rg < 4; ++rg)
          Of[((size_t)b * CH + lrow + rg) * T_ + col] = v[rg];
      } else {
        const int grow = itg * 128 + r0;
#pragma unroll
        for (int rg = 0; rg < 4; ++rg) {
          const size_t o = ((size_t)b * T_ + grow + rg) * D_ + col;
          Of[o] = v[rg] + Resid[o];
        }
      }
    }
  }
}

// ---------------------------------------------------------------------------
// Column-softmax stats over query axis i (valid i >= j), per 128-row slot.
// ---------------------------------------------------------------------------
__global__ __launch_bounds__(256)
void colstats_partial(const float* __restrict__ Sc, float* __restrict__ pm,
                      float* __restrict__ pd, int c) {
  const int j = blockIdx.x * 256 + threadIdx.x;
  const int b = blockIdx.y, s = blockIdx.z;
  const int gi0 = c * CH + s * 128;
  const float* Sb = Sc + ((size_t)b * CH + s * 128) * T_;
  float m = -INFINITY, d = 0.f;
  if (gi0 + 127 >= j) {
    for (int ii = 0; ii < 128; ++ii) {
      if (gi0 + ii >= j) {
        const float v = Sb[(size_t)ii * T_ + j];
        const float nm = fmaxf(m, v);
        d = d * __expf(m - nm) + __expf(v - nm);
        m = nm;
      }
    }
  }
  const int slot = c * (CH / 128) + s;
  const int idx = (slot * B_ + b) * T_ + j;
  pm[idx] = m;
  pd[idx] = d;
}

__global__ __launch_bounds__(256)
void colstats_combine(const float* __restrict__ pm, const float* __restrict__ pd,
                      float* __restrict__ mcol, float* __restrict__ rcol) {
  const int j = blockIdx.x * 256 + threadIdx.x;
  const int b = blockIdx.y;
  float m = -INFINITY, d = 0.f;
  for (int s = 0; s < NSLOT; ++s) {
    const int idx = (s * B_ + b) * T_ + j;
    const float pmv = pm[idx], pdv = pd[idx];
    if (pdv > 0.f) {
      const float nm = fmaxf(m, pmv);
      d = d * __expf(m - nm) + pdv * __expf(pmv - nm);
      m = nm;
    }
  }
  mcol[b * T_ + j] = m;
  rcol[b * T_ + j] = 1.f / (d * 32.f);   // fold post-softmax 1/sqrt(K)=1/32
}

// ---------------------------------------------------------------------------
// P(fp16) = exp(S - m_j) * rcol_j for j<=i, 0 for j>i (diag tiles).
// ---------------------------------------------------------------------------
__global__ __launch_bounds__(256)
void normalize_chunk(const float* __restrict__ Sc, f16* __restrict__ Pc,
                     const float* __restrict__ mcol, const float* __restrict__ rcol,
                     int rowTileOff) {
  const int jt = blockIdx.x, itl = blockIdx.y, b = blockIdx.z;
  const int itg = rowTileOff + itl;
  if (jt > itg) return;
  const float* Sb = Sc + (size_t)b * CH * T_;
  f16* Pb = Pc + (size_t)b * CH * T_;
  const int li0 = itl * 128, gi0 = itg * 128, j0 = jt * 128;
  const float* mc = mcol + b * T_;
  const float* rc = rcol + b * T_;
#pragma unroll 4
  for (int r = 0; r < 64; ++r) {
    const int idx = r * 256 + threadIdx.x;
    const int li = idx >> 7, lj = idx & 127;
    const int gi = gi0 + li, j = j0 + lj;
    const size_t off = (size_t)(li0 + li) * T_ + j;
    float v = 0.f;
    if (j <= gi) v = __expf(Sb[off] - mc[j]) * rc[j];
    Pb[off] = (f16)v;
  }
}

// ---------------------------------------------------------------------------
extern "C" void kernel_launch(void* const* d_in, const int* in_sizes, int n_in,
                              void* d_out, int out_size, void* d_ws, size_t ws_size,
                              hipStream_t stream) {
  const float* X  = (const float*)d_in[0];
  const float* Wq = (const float*)d_in[1];
  const float* bq = (const float*)d_in[2];
  const float* Wk = (const float*)d_in[3];
  const float* bk = (const float*)d_in[4];
  const float* Wv = (const float*)d_in[5];
  const float* bv = (const float*)d_in[6];
  float* out = (float*)d_out;

  // Workspace carve (~193 MB)
  char* p = (char*)d_ws;
  auto carve = [&](size_t bytes) { char* r = p; p += (bytes + 255) & ~(size_t)255; return r; };
  f16*   Xh   = (f16*)carve((size_t)B_ * T_ * D_ * 2);
  f16*   Wqt  = (f16*)carve((size_t)D_ * KSZ * 2);
  f16*   Wkt  = (f16*)carve((size_t)D_ * KSZ * 2);
  f16*   Wvt  = (f16*)carve((size_t)D_ * D_ * 2);
  f16*   Qh   = (f16*)carve((size_t)B_ * T_ * KSZ * 2);
  f16*   Kh   = (f16*)carve((size_t)B_ * T_ * KSZ * 2);
  f16*   Vt   = (f16*)carve((size_t)B_ * D_ * T_ * 2);
  float* Sc   = (float*)carve((size_t)B_ * CH * T_ * 4);
  f16*   Pc   = (f16*)carve((size_t)B_ * CH * T_ * 2);
  float* pm   = (float*)carve((size_t)NSLOT * B_ * T_ * 4);
  float* pd   = (float*)carve((size_t)NSLOT * B_ * T_ * 4);
  float* mcol = (float*)carve((size_t)B_ * T_ * 4);
  float* rcol = (float*)carve((size_t)B_ * T_ * 4);

  const dim3 blk(256);

  // Prep: casts + weight transposes
  cast_f16_kernel<<<dim3((B_ * T_ * D_ / 4) / 256), blk, 0, stream>>>(X, Xh);
  transcast_kernel<<<dim3((D_ * KSZ) / 256), blk, 0, stream>>>(Wq, Wqt);
  transcast_kernel<<<dim3((D_ * KSZ) / 256), blk, 0, stream>>>(Wk, Wkt);
  transcast_kernel<<<dim3((D_ * D_) / 256), blk, 0, stream>>>(Wv, Wvt);

  // Projections (MFMA): Qh/Kh fp16 [16384][1024]; Vt fp16 [b][v][t]
  gemm_nt<0><<<dim3(KSZ / 128, (B_ * T_) / 128, 1), blk, 0, stream>>>(Xh, Wqt, bq, Qh, nullptr, nullptr, 0);
  gemm_nt<0><<<dim3(KSZ / 128, (B_ * T_) / 128, 1), blk, 0, stream>>>(Xh, Wkt, bk, Kh, nullptr, nullptr, 0);
  gemm_nt<1><<<dim3(D_ / 128, (B_ * T_) / 128, 1), blk, 0, stream>>>(Xh, Wvt, bv, Vt, nullptr, nullptr, 0);

  // Pass A: QK chunks (MFMA) + column-softmax partial stats
  for (int c = 0; c < NCHUNK; ++c) {
    gemm_nt<2><<<dim3(T_ / 128, CH / 128, B_), blk, 0, stream>>>(Qh, Kh, nullptr, nullptr, Sc, nullptr, c * (CH / 128));
    colstats_partial<<<dim3(T_ / 256, B_, CH / 128), blk, 0, stream>>>(Sc, pm, pd, c);
  }
  colstats_combine<<<dim3(T_ / 256, B_), blk, 0, stream>>>(pm, pd, mcol, rcol);

  // Pass B: recompute QK, normalize to fp16 P, PV (MFMA) + residual
  for (int c = 0; c < NCHUNK; ++c) {
    gemm_nt<2><<<dim3(T_ / 128, CH / 128, B_), blk, 0, stream>>>(Qh, Kh, nullptr, nullptr, Sc, nullptr, c * (CH / 128));
    normalize_chunk<<<dim3(T_ / 128, CH / 128, B_), blk, 0, stream>>>(Sc, Pc, mcol, rcol, c * (CH / 128));
    gemm_nt<3><<<dim3(D_ / 128, CH / 128, B_), blk, 0, stream>>>(Pc, Vt, nullptr, nullptr, out, X, c * (CH / 128));
  }
}

// Round 5
// 963.583 us; speedup vs baseline: 6.3041x; 1.0419x over previous
//
#include <hip/hip_runtime.h>
#include <hip/hip_fp16.h>
#include <math.h>

// Problem constants: B=8, T=2048, D=1024, K_SIZE=1024, fp32 in/out.
#define B_   8
#define T_   2048
#define D_   1024
#define KSZ  1024
#define CH   512            // i-rows per S chunk
#define NCHUNK 4            // T_/CH
#define NSLOT 16            // T_/128 softmax partial slots

typedef _Float16 f16;
typedef _Float16 f16x8 __attribute__((ext_vector_type(8)));
typedef _Float16 f16x4 __attribute__((ext_vector_type(4)));
typedef float f32x4 __attribute__((ext_vector_type(4)));

#define GLOBAL_AS __attribute__((address_space(1)))
#define LDS_AS    __attribute__((address_space(3)))

// Async global->LDS, 16 B per lane. HW: LDS dest = wave-uniform base + lane*16.
static __device__ __forceinline__ void cp16(void* l, const void* g) {
  __builtin_amdgcn_global_load_lds((GLOBAL_AS void*)g, (LDS_AS void*)l, 16, 0, 0);
}

// ---------------------------------------------------------------------------
// Prep: fp32 -> fp16 cast (vectorized)
// ---------------------------------------------------------------------------
__global__ __launch_bounds__(256)
void cast_f16_kernel(const float* __restrict__ X, f16* __restrict__ Xh) {
  const size_t i = ((size_t)blockIdx.x * 256 + threadIdx.x) * 4;
  float4 v = *(const float4*)&X[i];
  f16x4 o = {(f16)v.x, (f16)v.y, (f16)v.z, (f16)v.w};
  *(f16x4*)&Xh[i] = o;
}

// Prep: W[k][n] -> Wt[n][k] fp16 (1024x1024)
__global__ __launch_bounds__(256)
void transcast_kernel(const float* __restrict__ W, f16* __restrict__ Wt) {
  const int idx = blockIdx.x * 256 + threadIdx.x;  // idx = n*1024 + k, k fast
  const int n = idx >> 10, k = idx & 1023;
  Wt[idx] = (f16)W[k * 1024 + n];
}

// ---------------------------------------------------------------------------
// Unified fp16 MFMA NT-GEMM: C[m,n] = sum_k A[m,k] * B[n,k]  (+ epilogue)
//  EP=0: proj Q/K  -> Oh fp16 [16384][1024], +bias
//  EP=1: proj V    -> Vt fp16 [b][v][t] (transposed store), +bias
//  EP=2: QK chunk  -> Of fp32 S[b][CH][T_], triangular tile skip
//  EP=3: PV chunk  -> Of fp32 out[b][t][v] = acc + Resid (residual X)
// Staging: 2x global_load_lds dwordx4 per matrix per K-step — full 8192 B
// tile coverage (128 rows x 32 k f16).  Issue r covers LDS f16 idx
// t*8 + r*2048 -> row 64r + t/4, k (t%4)*8; unpadded [row][32k] layout (m97).
// Fragments: A/B = row(lane&15), k(quad*8+j); C/D row=(lane>>4)*4+reg.
// ---------------------------------------------------------------------------
template <int EP>
__global__ __launch_bounds__(256)
void gemm_nt(const f16* __restrict__ A, const f16* __restrict__ Bm,
             const float* __restrict__ bias, f16* __restrict__ Oh,
             float* __restrict__ Of, const float* __restrict__ Resid,
             int rowTileOff) {
  constexpr int LDA = (EP == 3) ? T_ : KSZ;
  constexpr int LDB = (EP == 3) ? T_ : KSZ;
  const int jt = blockIdx.x, it = blockIdx.y, b = blockIdx.z;
  const int itg = rowTileOff + it;
  if (EP == 2 && jt > itg) return;
  const int kend = (EP == 3) ? (itg + 1) * 128 : KSZ;

  const f16* Ab = A;
  const f16* Bb = Bm;
  if (EP == 2) { Ab += (size_t)b * T_ * KSZ; Bb += (size_t)b * T_ * KSZ; }
  if (EP == 3) { Ab += (size_t)b * CH * T_;  Bb += (size_t)b * D_ * T_; }

  const int arow0 = (EP == 2) ? itg * 128 : it * 128;  // EP3: local chunk rows
  const int col0 = jt * 128;

  __shared__ f16 Ash[128 * 32];
  __shared__ f16 Bsh[128 * 32];

  const int tid = threadIdx.x;
  const int srow = tid >> 2, sk = (tid & 3) * 8;
  const f16* ag0 = Ab + (size_t)(arow0 + srow) * LDA + sk;
  const f16* ag1 = Ab + (size_t)(arow0 + 64 + srow) * LDA + sk;
  const f16* bg0 = Bb + (size_t)(col0 + srow) * LDB + sk;
  const f16* bg1 = Bb + (size_t)(col0 + 64 + srow) * LDB + sk;

  const int lane = tid & 63, wv = tid >> 6;
  f16* aslot0 = &Ash[wv * 512];          // rows 0..63   (wave-uniform base)
  f16* aslot1 = &Ash[2048 + wv * 512];   // rows 64..127
  f16* bslot0 = &Bsh[wv * 512];
  f16* bslot1 = &Bsh[2048 + wv * 512];

  const int wm = (wv & 1) * 64, wn = (wv >> 1) * 64;
  const int fr = lane & 15, quad = lane >> 4;

  f32x4 acc[4][4] = {};

  for (int k0 = 0; k0 < kend; k0 += 32) {
    __syncthreads();                 // previous tile fully consumed
    cp16(aslot0, ag0 + k0);
    cp16(aslot1, ag1 + k0);
    cp16(bslot0, bg0 + k0);
    cp16(bslot1, bg1 + k0);
    __syncthreads();                 // drains vmcnt -> LDS visible
    f16x8 af[4], bf[4];
#pragma unroll
    for (int mi = 0; mi < 4; ++mi)
      af[mi] = *(const f16x8*)&Ash[(wm + mi * 16 + fr) * 32 + quad * 8];
#pragma unroll
    for (int ni = 0; ni < 4; ++ni)
      bf[ni] = *(const f16x8*)&Bsh[(wn + ni * 16 + fr) * 32 + quad * 8];
#pragma unroll
    for (int mi = 0; mi < 4; ++mi)
#pragma unroll
      for (int ni = 0; ni < 4; ++ni)
        acc[mi][ni] = __builtin_amdgcn_mfma_f32_16x16x32_f16(af[mi], bf[ni], acc[mi][ni], 0, 0, 0);
  }

#pragma unroll
  for (int mi = 0; mi < 4; ++mi) {
#pragma unroll
    for (int ni = 0; ni < 4; ++ni) {
      const int col = col0 + wn + ni * 16 + fr;
      float bc = 0.f;
      if (EP == 0 || EP == 1) bc = bias[col];
      const int r0 = wm + mi * 16 + quad * 4;
      f32x4 v = acc[mi][ni];
      if (EP == 0) {
        const int grow = it * 128 + r0;
#pragma unroll
        for (int rg = 0; rg < 4; ++rg)
          Oh[(size_t)(grow + rg) * KSZ + col] = (f16)(v[rg] + bc);
      } else if (EP == 1) {
        const int grow = it * 128 + r0;
        const int bb = grow >> 11, t0 = grow & 2047;
        f16x4 pk;
#pragma unroll
        for (int rg = 0; rg < 4; ++rg) pk[rg] = (f16)(v[rg] + bc);
        *(f16x4*)&Oh[((size_t)bb * D_ + col) * T_ + t0] = pk;
      } else if (EP == 2) {
        const int lrow = it * 128 + r0;
#pragma unroll
        for (int rg = 0; rg < 4; ++rg)
          Of[((size_t)b * CH + lrow + rg) * T_ + col] = v[rg];
      } else {
        const int grow = itg * 128 + r0;
#pragma unroll
        for (int rg = 0; rg < 4; ++rg) {
          const size_t o = ((size_t)b * T_ + grow + rg) * D_ + col;
          Of[o] = v[rg] + Resid[o];
        }
      }
    }
  }
}

// ---------------------------------------------------------------------------
// Column-softmax stats over query axis i (valid i >= j), per 128-row slot.
// ---------------------------------------------------------------------------
__global__ __launch_bounds__(256)
void colstats_partial(const float* __restrict__ Sc, float* __restrict__ pm,
                      float* __restrict__ pd, int c) {
  const int j = blockIdx.x * 256 + threadIdx.x;
  const int b = blockIdx.y, s = blockIdx.z;
  const int gi0 = c * CH + s * 128;
  const float* Sb = Sc + ((size_t)b * CH + s * 128) * T_;
  float m = -INFINITY, d = 0.f;
  if (gi0 + 127 >= j) {
    for (int ii = 0; ii < 128; ++ii) {
      if (gi0 + ii >= j) {
        const float v = Sb[(size_t)ii * T_ + j];
        const float nm = fmaxf(m, v);
        d = d * __expf(m - nm) + __expf(v - nm);
        m = nm;
      }
    }
  }
  const int slot = c * (CH / 128) + s;
  const int idx = (slot * B_ + b) * T_ + j;
  pm[idx] = m;
  pd[idx] = d;
}

__global__ __launch_bounds__(256)
void colstats_combine(const float* __restrict__ pm, const float* __restrict__ pd,
                      float* __restrict__ mcol, float* __restrict__ rcol) {
  const int j = blockIdx.x * 256 + threadIdx.x;
  const int b = blockIdx.y;
  float m = -INFINITY, d = 0.f;
  for (int s = 0; s < NSLOT; ++s) {
    const int idx = (s * B_ + b) * T_ + j;
    const float pmv = pm[idx], pdv = pd[idx];
    if (pdv > 0.f) {
      const float nm = fmaxf(m, pmv);
      d = d * __expf(m - nm) + pdv * __expf(pmv - nm);
      m = nm;
    }
  }
  mcol[b * T_ + j] = m;
  rcol[b * T_ + j] = 1.f / (d * 32.f);   // fold post-softmax 1/sqrt(K)=1/32
}

// ---------------------------------------------------------------------------
// P(fp16) = exp(S - m_j) * rcol_j for j<=i, 0 for j>i (diag tiles).
// ---------------------------------------------------------------------------
__global__ __launch_bounds__(256)
void normalize_chunk(const float* __restrict__ Sc, f16* __restrict__ Pc,
                     const float* __restrict__ mcol, const float* __restrict__ rcol,
                     int rowTileOff) {
  const int jt = blockIdx.x, itl = blockIdx.y, b = blockIdx.z;
  const int itg = rowTileOff + itl;
  if (jt > itg) return;
  const float* Sb = Sc + (size_t)b * CH * T_;
  f16* Pb = Pc + (size_t)b * CH * T_;
  const int li0 = itl * 128, gi0 = itg * 128, j0 = jt * 128;
  const float* mc = mcol + b * T_;
  const float* rc = rcol + b * T_;
#pragma unroll 4
  for (int r = 0; r < 64; ++r) {
    const int idx = r * 256 + threadIdx.x;
    const int li = idx >> 7, lj = idx & 127;
    const int gi = gi0 + li, j = j0 + lj;
    const size_t off = (size_t)(li0 + li) * T_ + j;
    float v = 0.f;
    if (j <= gi) v = __expf(Sb[off] - mc[j]) * rc[j];
    Pb[off] = (f16)v;
  }
}

// ---------------------------------------------------------------------------
extern "C" void kernel_launch(void* const* d_in, const int* in_sizes, int n_in,
                              void* d_out, int out_size, void* d_ws, size_t ws_size,
                              hipStream_t stream) {
  const float* X  = (const float*)d_in[0];
  const float* Wq = (const float*)d_in[1];
  const float* bq = (const float*)d_in[2];
  const float* Wk = (const float*)d_in[3];
  const float* bk = (const float*)d_in[4];
  const float* Wv = (const float*)d_in[5];
  const float* bv = (const float*)d_in[6];
  float* out = (float*)d_out;

  // Workspace carve (~193 MB)
  char* p = (char*)d_ws;
  auto carve = [&](size_t bytes) { char* r = p; p += (bytes + 255) & ~(size_t)255; return r; };
  f16*   Xh   = (f16*)carve((size_t)B_ * T_ * D_ * 2);
  f16*   Wqt  = (f16*)carve((size_t)D_ * KSZ * 2);
  f16*   Wkt  = (f16*)carve((size_t)D_ * KSZ * 2);
  f16*   Wvt  = (f16*)carve((size_t)D_ * D_ * 2);
  f16*   Qh   = (f16*)carve((size_t)B_ * T_ * KSZ * 2);
  f16*   Kh   = (f16*)carve((size_t)B_ * T_ * KSZ * 2);
  f16*   Vt   = (f16*)carve((size_t)B_ * D_ * T_ * 2);
  float* Sc   = (float*)carve((size_t)B_ * CH * T_ * 4);
  f16*   Pc   = (f16*)carve((size_t)B_ * CH * T_ * 2);
  float* pm   = (float*)carve((size_t)NSLOT * B_ * T_ * 4);
  float* pd   = (float*)carve((size_t)NSLOT * B_ * T_ * 4);
  float* mcol = (float*)carve((size_t)B_ * T_ * 4);
  float* rcol = (float*)carve((size_t)B_ * T_ * 4);

  const dim3 blk(256);

  // Prep: casts + weight transposes
  cast_f16_kernel<<<dim3((B_ * T_ * D_ / 4) / 256), blk, 0, stream>>>(X, Xh);
  transcast_kernel<<<dim3((D_ * KSZ) / 256), blk, 0, stream>>>(Wq, Wqt);
  transcast_kernel<<<dim3((D_ * KSZ) / 256), blk, 0, stream>>>(Wk, Wkt);
  transcast_kernel<<<dim3((D_ * D_) / 256), blk, 0, stream>>>(Wv, Wvt);

  // Projections (MFMA): Qh/Kh fp16 [16384][1024]; Vt fp16 [b][v][t]
  gemm_nt<0><<<dim3(KSZ / 128, (B_ * T_) / 128, 1), blk, 0, stream>>>(Xh, Wqt, bq, Qh, nullptr, nullptr, 0);
  gemm_nt<0><<<dim3(KSZ / 128, (B_ * T_) / 128, 1), blk, 0, stream>>>(Xh, Wkt, bk, Kh, nullptr, nullptr, 0);
  gemm_nt<1><<<dim3(D_ / 128, (B_ * T_) / 128, 1), blk, 0, stream>>>(Xh, Wvt, bv, Vt, nullptr, nullptr, 0);

  // Pass A: QK chunks (MFMA) + column-softmax partial stats
  for (int c = 0; c < NCHUNK; ++c) {
    gemm_nt<2><<<dim3(T_ / 128, CH / 128, B_), blk, 0, stream>>>(Qh, Kh, nullptr, nullptr, Sc, nullptr, c * (CH / 128));
    colstats_partial<<<dim3(T_ / 256, B_, CH / 128), blk, 0, stream>>>(Sc, pm, pd, c);
  }
  colstats_combine<<<dim3(T_ / 256, B_), blk, 0, stream>>>(pm, pd, mcol, rcol);

  // Pass B: recompute QK, normalize to fp16 P, PV (MFMA) + residual
  for (int c = 0; c < NCHUNK; ++c) {
    gemm_nt<2><<<dim3(T_ / 128, CH / 128, B_), blk, 0, stream>>>(Qh, Kh, nullptr, nullptr, Sc, nullptr, c * (CH / 128));
    normalize_chunk<<<dim3(T_ / 128, CH / 128, B_), blk, 0, stream>>>(Sc, Pc, mcol, rcol, c * (CH / 128));
    gemm_nt<3><<<dim3(D_ / 128, CH / 128, B_), blk, 0, stream>>>(Pc, Vt, nullptr, nullptr, out, X, c * (CH / 128));
  }
}

// Round 7
// 612.494 us; speedup vs baseline: 9.9177x; 1.5732x over previous
//
#include <hip/hip_runtime.h>
#include <hip/hip_fp16.h>
#include <math.h>

// Problem constants: B=8, T=2048, D=1024, K_SIZE=1024, fp32 in/out.
#define B_   8
#define T_   2048
#define D_   1024
#define KSZ  1024
#define NSLOT 16            // T_/128 softmax partial slots (one per row-tile)

typedef _Float16 f16;
typedef _Float16 f16x8 __attribute__((ext_vector_type(8)));
typedef _Float16 f16x4 __attribute__((ext_vector_type(4)));
typedef float f32x4 __attribute__((ext_vector_type(4)));

#define GLOBAL_AS __attribute__((address_space(1)))
#define LDS_AS    __attribute__((address_space(3)))

// Async global->LDS, 16 B per lane. HW: LDS dest = wave-uniform base + lane*16.
static __device__ __forceinline__ void cp16(void* l, const void* g) {
  __builtin_amdgcn_global_load_lds((GLOBAL_AS void*)g, (LDS_AS void*)l, 16, 0, 0);
}

// Guarded online-softmax pair combine: (m1,d1) += (m2,d2)
static __device__ __forceinline__ void sm_combine(float& m1, float& d1,
                                                  float m2, float d2) {
  const float nm = fmaxf(m1, m2);
  float d = 0.f;
  if (d1 > 0.f) d += d1 * __expf(m1 - nm);
  if (d2 > 0.f) d += d2 * __expf(m2 - nm);
  m1 = nm; d1 = d;
}

// ---------------------------------------------------------------------------
// Prep: fp32 -> fp16 cast (vectorized)
// ---------------------------------------------------------------------------
__global__ __launch_bounds__(256)
void cast_f16_kernel(const float* __restrict__ X, f16* __restrict__ Xh) {
  const size_t i = ((size_t)blockIdx.x * 256 + threadIdx.x) * 4;
  float4 v = *(const float4*)&X[i];
  f16x4 o = {(f16)v.x, (f16)v.y, (f16)v.z, (f16)v.w};
  *(f16x4*)&Xh[i] = o;
}

// Prep: W[k][n] -> Wt[n][k] fp16 (1024x1024)
__global__ __launch_bounds__(256)
void transcast_kernel(const float* __restrict__ W, f16* __restrict__ Wt) {
  const int idx = blockIdx.x * 256 + threadIdx.x;  // idx = n*1024 + k, k fast
  const int n = idx >> 10, k = idx & 1023;
  Wt[idx] = (f16)W[k * 1024 + n];
}

// ---------------------------------------------------------------------------
// fp16 MFMA NT-GEMM (projections + PV): C[m,n] = sum_k A[m,k]*B[n,k]
//  EP=0: proj Q/K -> Oh fp16 [16384][1024], +bias
//  EP=1: proj V   -> Vt fp16 [b][v][t] (transposed store), +bias
//  EP=3: PV       -> out fp32 [b][t][v] = acc + Resid; A = P [b][T][T] fp16
// Staging: 2x global_load_lds dwordx4 per matrix per 32-K step (m97 layout).
// ---------------------------------------------------------------------------
template <int EP>
__global__ __launch_bounds__(256)
void gemm_nt(const f16* __restrict__ A, const f16* __restrict__ Bm,
             const float* __restrict__ bias, f16* __restrict__ Oh,
             float* __restrict__ Of, const float* __restrict__ Resid) {
  constexpr int LDA = (EP == 3) ? T_ : KSZ;
  constexpr int LDB = (EP == 3) ? T_ : KSZ;
  const int jt = blockIdx.x, b = blockIdx.z;
  // PV: reverse row-tile order so the longest blocks (large itg) launch first.
  const int it = (EP == 3) ? ((int)gridDim.y - 1 - (int)blockIdx.y)
                           : (int)blockIdx.y;
  const int itg = it;
  const int kend = (EP == 3) ? (itg + 1) * 128 : KSZ;

  const f16* Ab = A;
  const f16* Bb = Bm;
  if (EP == 3) { Ab += (size_t)b * T_ * T_; Bb += (size_t)b * D_ * T_; }

  const int arow0 = it * 128;
  const int col0 = jt * 128;

  __shared__ f16 Ash[128 * 32];
  __shared__ f16 Bsh[128 * 32];

  const int tid = threadIdx.x;
  const int srow = tid >> 2, sk = (tid & 3) * 8;
  const f16* ag0 = Ab + (size_t)(arow0 + srow) * LDA + sk;
  const f16* ag1 = Ab + (size_t)(arow0 + 64 + srow) * LDA + sk;
  const f16* bg0 = Bb + (size_t)(col0 + srow) * LDB + sk;
  const f16* bg1 = Bb + (size_t)(col0 + 64 + srow) * LDB + sk;

  const int lane = tid & 63, wv = tid >> 6;
  f16* aslot0 = &Ash[wv * 512];
  f16* aslot1 = &Ash[2048 + wv * 512];
  f16* bslot0 = &Bsh[wv * 512];
  f16* bslot1 = &Bsh[2048 + wv * 512];

  const int wm = (wv & 1) * 64, wn = (wv >> 1) * 64;
  const int fr = lane & 15, quad = lane >> 4;

  f32x4 acc[4][4] = {};

  for (int k0 = 0; k0 < kend; k0 += 32) {
    __syncthreads();
    cp16(aslot0, ag0 + k0);
    cp16(aslot1, ag1 + k0);
    cp16(bslot0, bg0 + k0);
    cp16(bslot1, bg1 + k0);
    __syncthreads();
    f16x8 af[4], bf[4];
#pragma unroll
    for (int mi = 0; mi < 4; ++mi)
      af[mi] = *(const f16x8*)&Ash[(wm + mi * 16 + fr) * 32 + quad * 8];
#pragma unroll
    for (int ni = 0; ni < 4; ++ni)
      bf[ni] = *(const f16x8*)&Bsh[(wn + ni * 16 + fr) * 32 + quad * 8];
#pragma unroll
    for (int mi = 0; mi < 4; ++mi)
#pragma unroll
      for (int ni = 0; ni < 4; ++ni)
        acc[mi][ni] = __builtin_amdgcn_mfma_f32_16x16x32_f16(af[mi], bf[ni], acc[mi][ni], 0, 0, 0);
  }

#pragma unroll
  for (int mi = 0; mi < 4; ++mi) {
#pragma unroll
    for (int ni = 0; ni < 4; ++ni) {
      const int col = col0 + wn + ni * 16 + fr;
      float bc = 0.f;
      if (EP == 0 || EP == 1) bc = bias[col];
      const int r0 = wm + mi * 16 + quad * 4;
      f32x4 v = acc[mi][ni];
      if (EP == 0) {
        const int grow = it * 128 + r0;
#pragma unroll
        for (int rg = 0; rg < 4; ++rg)
          Oh[(size_t)(grow + rg) * KSZ + col] = (f16)(v[rg] + bc);
      } else if (EP == 1) {
        const int grow = it * 128 + r0;
        const int bb = grow >> 11, t0 = grow & 2047;
        f16x4 pk;
#pragma unroll
        for (int rg = 0; rg < 4; ++rg) pk[rg] = (f16)(v[rg] + bc);
        *(f16x4*)&Oh[((size_t)bb * D_ + col) * T_ + t0] = pk;
      } else {
        const int grow = itg * 128 + r0;
#pragma unroll
        for (int rg = 0; rg < 4; ++rg) {
          const size_t o = ((size_t)b * T_ + grow + rg) * D_ + col;
          Of[o] = v[rg] + Resid[o];
        }
      }
    }
  }
}

// ---------------------------------------------------------------------------
// Triangular QK kernel. S[i,j] = Q_i . K_j for tiles jt <= it.
//  STATS=1 (pass A): per-column (m, sum-exp) over the block's 128 rows ->
//                    pm/pd[it][b][j]. No S storage.
//  STATS=0 (pass B): P[i,j] = exp(S - mcol_j)*rcol_j (0 for j>i) -> Pc fp16.
// ---------------------------------------------------------------------------
template <int STATS>
__global__ __launch_bounds__(256)
void qk_tri(const f16* __restrict__ Q, const f16* __restrict__ Km,
            float* __restrict__ pm, float* __restrict__ pd,
            const float* __restrict__ mcol, const float* __restrict__ rcol,
            f16* __restrict__ Pc) {
  const int jt = blockIdx.x, itg = blockIdx.y, b = blockIdx.z;
  if (jt > itg) return;
  const bool diag = (jt == itg);

  const f16* Ab = Q  + (size_t)b * T_ * KSZ;
  const f16* Bb = Km + (size_t)b * T_ * KSZ;
  const int arow0 = itg * 128, col0 = jt * 128;

  __shared__ f16 Ash[128 * 32];
  __shared__ f16 Bsh[128 * 32];
  __shared__ float red_m[4][64];
  __shared__ float red_d[4][64];

  const int tid = threadIdx.x;
  const int srow = tid >> 2, sk = (tid & 3) * 8;
  const f16* ag0 = Ab + (size_t)(arow0 + srow) * KSZ + sk;
  const f16* ag1 = Ab + (size_t)(arow0 + 64 + srow) * KSZ + sk;
  const f16* bg0 = Bb + (size_t)(col0 + srow) * KSZ + sk;
  const f16* bg1 = Bb + (size_t)(col0 + 64 + srow) * KSZ + sk;

  const int lane = tid & 63, wv = tid >> 6;
  f16* aslot0 = &Ash[wv * 512];
  f16* aslot1 = &Ash[2048 + wv * 512];
  f16* bslot0 = &Bsh[wv * 512];
  f16* bslot1 = &Bsh[2048 + wv * 512];

  const int wm = (wv & 1) * 64, wn = (wv >> 1) * 64;
  const int fr = lane & 15, quad = lane >> 4;

  f32x4 acc[4][4] = {};

  for (int k0 = 0; k0 < KSZ; k0 += 32) {
    __syncthreads();
    cp16(aslot0, ag0 + k0);
    cp16(aslot1, ag1 + k0);
    cp16(bslot0, bg0 + k0);
    cp16(bslot1, bg1 + k0);
    __syncthreads();
    f16x8 af[4], bf[4];
#pragma unroll
    for (int mi = 0; mi < 4; ++mi)
      af[mi] = *(const f16x8*)&Ash[(wm + mi * 16 + fr) * 32 + quad * 8];
#pragma unroll
    for (int ni = 0; ni < 4; ++ni)
      bf[ni] = *(const f16x8*)&Bsh[(wn + ni * 16 + fr) * 32 + quad * 8];
#pragma unroll
    for (int mi = 0; mi < 4; ++mi)
#pragma unroll
      for (int ni = 0; ni < 4; ++ni)
        acc[mi][ni] = __builtin_amdgcn_mfma_f32_16x16x32_f16(af[mi], bf[ni], acc[mi][ni], 0, 0, 0);
  }

  if (STATS) {
    // Per-column (m, d) over this block's 128 rows. Two-pass: max, then exp.
#pragma unroll
    for (int ni = 0; ni < 4; ++ni) {
      const int gj = col0 + wn + ni * 16 + fr;
      float lm = -INFINITY;
#pragma unroll
      for (int mi = 0; mi < 4; ++mi) {
        const int gi0 = arow0 + wm + mi * 16 + quad * 4;
#pragma unroll
        for (int rg = 0; rg < 4; ++rg)
          if (!diag || (gi0 + rg >= gj)) lm = fmaxf(lm, acc[mi][ni][rg]);
      }
      float ld = 0.f;
#pragma unroll
      for (int mi = 0; mi < 4; ++mi) {
        const int gi0 = arow0 + wm + mi * 16 + quad * 4;
#pragma unroll
        for (int rg = 0; rg < 4; ++rg)
          if (!diag || (gi0 + rg >= gj)) ld += __expf(acc[mi][ni][rg] - lm);
      }
      // Butterfly across the 4 quads (lanes fr, fr+16, fr+32, fr+48).
      sm_combine(lm, ld, __shfl_xor(lm, 16), __shfl_xor(ld, 16));
      sm_combine(lm, ld, __shfl_xor(lm, 32), __shfl_xor(ld, 32));
      if (quad == 0) { red_m[wv][ni * 16 + fr] = lm; red_d[wv][ni * 16 + fr] = ld; }
    }
    __syncthreads();
    if (tid < 128) {
      const int c = tid;                     // block-local column 0..127
      const int w0 = (c < 64) ? 0 : 2;       // waves (w0, w0+1) cover col c
      const int cc = c & 63;
      float m1 = red_m[w0][cc], d1 = red_d[w0][cc];
      sm_combine(m1, d1, red_m[w0 + 1][cc], red_d[w0 + 1][cc]);
      const int idx = (itg * B_ + b) * T_ + col0 + c;
      pm[idx] = m1;
      pd[idx] = d1;
    }
  } else {
    // P = exp(S - m_j) * r_j for j<=i, 0 above diagonal; fp16 store.
    f16* Pb = Pc + (size_t)b * T_ * T_;
    const float* mc = mcol + b * T_;
    const float* rc = rcol + b * T_;
#pragma unroll
    for (int ni = 0; ni < 4; ++ni) {
      const int gj = col0 + wn + ni * 16 + fr;
      const float mj = mc[gj], rj = rc[gj];
#pragma unroll
      for (int mi = 0; mi < 4; ++mi) {
        const int gi0 = arow0 + wm + mi * 16 + quad * 4;
#pragma unroll
        for (int rg = 0; rg < 4; ++rg) {
          float v = 0.f;
          if (!diag || (gi0 + rg >= gj))
            v = __expf(acc[mi][ni][rg] - mj) * rj;
          Pb[(size_t)(gi0 + rg) * T_ + gj] = (f16)v;
        }
      }
    }
  }
}

// ---------------------------------------------------------------------------
// Combine NSLOT partials per column; fold 1/sqrt(K)=1/32 into rcol.
// ---------------------------------------------------------------------------
__global__ __launch_bounds__(256)
void colstats_combine(const float* __restrict__ pm, const float* __restrict__ pd,
                      float* __restrict__ mcol, float* __restrict__ rcol) {
  const int j = blockIdx.x * 256 + threadIdx.x;
  const int b = blockIdx.y;
  float m = -INFINITY, d = 0.f;
  for (int s = 0; s < NSLOT; ++s) {
    const int idx = (s * B_ + b) * T_ + j;
    const float pmv = pm[idx], pdv = pd[idx];
    if (pdv > 0.f) sm_combine(m, d, pmv, pdv);
  }
  mcol[b * T_ + j] = m;
  rcol[b * T_ + j] = 1.f / (d * 32.f);
}

// ---------------------------------------------------------------------------
extern "C" void kernel_launch(void* const* d_in, const int* in_sizes, int n_in,
                              void* d_out, int out_size, void* d_ws, size_t ws_size,
                              hipStream_t stream) {
  const float* X  = (const float*)d_in[0];
  const float* Wq = (const float*)d_in[1];
  const float* bq = (const float*)d_in[2];
  const float* Wk = (const float*)d_in[3];
  const float* bk = (const float*)d_in[4];
  const float* Wv = (const float*)d_in[5];
  const float* bv = (const float*)d_in[6];
  float* out = (float*)d_out;

  // Workspace carve (~210 MB)
  char* p = (char*)d_ws;
  auto carve = [&](size_t bytes) { char* r = p; p += (bytes + 255) & ~(size_t)255; return r; };
  f16*   Xh   = (f16*)carve((size_t)B_ * T_ * D_ * 2);
  f16*   Wqt  = (f16*)carve((size_t)D_ * KSZ * 2);
  f16*   Wkt  = (f16*)carve((size_t)D_ * KSZ * 2);
  f16*   Wvt  = (f16*)carve((size_t)D_ * D_ * 2);
  f16*   Qh   = (f16*)carve((size_t)B_ * T_ * KSZ * 2);
  f16*   Kh   = (f16*)carve((size_t)B_ * T_ * KSZ * 2);
  f16*   Vt   = (f16*)carve((size_t)B_ * D_ * T_ * 2);
  f16*   Pc   = (f16*)carve((size_t)B_ * T_ * T_ * 2);
  float* pm   = (float*)carve((size_t)NSLOT * B_ * T_ * 4);
  float* pd   = (float*)carve((size_t)NSLOT * B_ * T_ * 4);
  float* mcol = (float*)carve((size_t)B_ * T_ * 4);
  float* rcol = (float*)carve((size_t)B_ * T_ * 4);

  const dim3 blk(256);

  // Prep: casts + weight transposes; zero pd (skipped tiles never write it).
  hipMemsetAsync(pd, 0, (size_t)NSLOT * B_ * T_ * 4, stream);
  cast_f16_kernel<<<dim3((B_ * T_ * D_ / 4) / 256), blk, 0, stream>>>(X, Xh);
  transcast_kernel<<<dim3((D_ * KSZ) / 256), blk, 0, stream>>>(Wq, Wqt);
  transcast_kernel<<<dim3((D_ * KSZ) / 256), blk, 0, stream>>>(Wk, Wkt);
  transcast_kernel<<<dim3((D_ * D_) / 256), blk, 0, stream>>>(Wv, Wvt);

  // Projections (MFMA)
  gemm_nt<0><<<dim3(KSZ / 128, (B_ * T_) / 128, 1), blk, 0, stream>>>(Xh, Wqt, bq, Qh, nullptr, nullptr);
  gemm_nt<0><<<dim3(KSZ / 128, (B_ * T_) / 128, 1), blk, 0, stream>>>(Xh, Wkt, bk, Kh, nullptr, nullptr);
  gemm_nt<1><<<dim3(D_ / 128, (B_ * T_) / 128, 1), blk, 0, stream>>>(Xh, Wvt, bv, Vt, nullptr, nullptr);

  // Pass A: fused QK + per-tile column softmax stats (no S storage)
  qk_tri<1><<<dim3(T_ / 128, T_ / 128, B_), blk, 0, stream>>>(Qh, Kh, pm, pd, nullptr, nullptr, nullptr);
  colstats_combine<<<dim3(T_ / 256, B_), blk, 0, stream>>>(pm, pd, mcol, rcol);

  // Pass B: fused QK + normalize -> fp16 P (full triangle)
  qk_tri<0><<<dim3(T_ / 128, T_ / 128, B_), blk, 0, stream>>>(Qh, Kh, nullptr, nullptr, mcol, rcol, Pc);

  // PV + residual
  gemm_nt<3><<<dim3(D_ / 128, T_ / 128, B_), blk, 0, stream>>>(Pc, Vt, nullptr, nullptr, out, X);
}